// Round 11
// baseline (1297.730 us; speedup 1.0000x reference)
//
#include <hip/hip_runtime.h>
#include <hip/hip_fp16.h>

#define NN 25000
#define EE 400000
#define FIN 128
#define FE 16
#define CH 32
#define SLOPE 0.01f
#define PROJ_BLOCKS 391   // ceil(25000/64)
#define AUX_BLOCKS 128               // 4 WtP blocks + 124 aggr-zero blocks
#define W16_SHORTS (1024 * 16)       // 32KB weight image, 16 shorts/row
#define NCH (EE / 32)                // 12500 chunks of 32 edges (exact)
#define EBLK 1024                    // k_edge blocks
#define GSTRIDE (EBLK * 4)           // 4096 waves, grid-stride in chunks

typedef __attribute__((ext_vector_type(8))) short bf16x8;
typedef __attribute__((ext_vector_type(4))) float f32x4;
typedef __attribute__((ext_vector_type(16))) float f32x16;

__device__ __forceinline__ float lrelu(float v) { return fmaxf(v, SLOPE * v); }

// float -> bf16 bits, round-to-nearest-even
__device__ __forceinline__ short f2bf(float f) {
    union { float f; unsigned u; } v; v.f = f;
    unsigned r = (v.u + 0x7fffu + ((v.u >> 16) & 1u)) >> 16;
    return (short)r;
}

__device__ __forceinline__ bf16x8 cvt8(const float4& a, const float4& b) {
    return (bf16x8){f2bf(a.x), f2bf(a.y), f2bf(a.z), f2bf(a.w),
                    f2bf(b.x), f2bf(b.y), f2bf(b.z), f2bf(b.w)};
}

// ---------------- Kernel 1: fused prep (R10, unchanged; aggrH now plain [node][o] f16)
__global__ void __launch_bounds__(256)
k_pre(const float* __restrict__ x, const float* __restrict__ W_in,
      const float* __restrict__ b_in, const float* __restrict__ W_edge,
      const float* __restrict__ b_edge,
      float* __restrict__ h, __half* __restrict__ aggrH, short* __restrict__ WtP16) {
    __shared__ short Wt1[CH * 136];
    int tid = threadIdx.x;

    if (blockIdx.x >= PROJ_BLOCKS) {
        int ab = blockIdx.x - PROJ_BLOCKS;
        if (ab < 4) {
            int co = ab * 256 + tid;                       // 0..1023
            short row[16] __attribute__((aligned(16)));
#pragma unroll
            for (int k = 0; k < 16; k++) row[k] = f2bf(W_edge[k * 1024 + co]);
            uint4* dstp = (uint4*)(WtP16 + co * 16);       // co*32B, 16B-aligned
            dstp[0] = ((uint4*)row)[0]; dstp[1] = ((uint4*)row)[1];
        } else {
            int t = (ab - 4) * 256 + tid;
            uint4 z = make_uint4(0u, 0u, 0u, 0u);
            for (int i = t; i < NN * CH * 2 / 16; i += (AUX_BLOCKS - 4) * 256)
                ((uint4*)aggrH)[i] = z;
        }
        return;
    }

#pragma unroll
    for (int i = 0; i < 16; i++) {
        int id = tid + 256 * i;           // id = k*32 + c
        int k = id >> 5, c = id & 31;
        Wt1[c * 136 + k] = f2bf(W_in[id]);
    }
    __syncthreads();

    int wave = tid >> 6, lane = tid & 63;
    int n16 = lane & 15, quad = lane >> 4;
    int node0 = blockIdx.x * 64 + wave * 16;

    f32x4 D[2];
#pragma unroll
    for (int ch = 0; ch < 2; ch++) {
        float bb = b_in[ch * 16 + n16];
        D[ch] = (f32x4){bb, bb, bb, bb};
    }
    int arow = node0 + n16; if (arow >= NN) arow = NN - 1;
#pragma unroll
    for (int kb = 0; kb < 4; kb++) {
        const float4* xp = (const float4*)(x + (size_t)arow * FIN + kb * 32 + quad * 8);
        float4 xa = xp[0], xb = xp[1];
        bf16x8 A = cvt8(xa, xb);
#pragma unroll
        for (int ch = 0; ch < 2; ch++) {
            bf16x8 B = *(const bf16x8*)&Wt1[(ch * 16 + n16) * 136 + kb * 32 + quad * 8];
            D[ch] = __builtin_amdgcn_mfma_f32_16x16x32_bf16(A, B, D[ch], 0, 0, 0);
        }
    }
#pragma unroll
    for (int ch = 0; ch < 2; ch++)
#pragma unroll
        for (int r = 0; r < 4; r++) {
            int nn = node0 + quad * 4 + r;
            if (nn < NN) h[(size_t)nn * CH + ch * 16 + n16] = lrelu(D[ch][r]);
        }
}

// ---------------- Kernel 2: BARRIER-FREE edge kernel, 32x32x16 MFMA, h in registers
// R10 post-mortem: 5 structures floor at 77-90us, all pipes <=50%; shared invariants
// were (a) 2 barriers/tile lockstep, (b) half-empty K=32 MFMAs, (c) ~1700 LDS cyc/wave/tile.
// This design removes all three:
//  * D[co][edge] = mfma_32x32x16(A = W16 rows (LDS b128, dense-1KB pattern), B = ea (regs)).
//    K=16 = FE exact (no padding); 32 MFMAs + 32 LDS reads per 32-edge chunk per wave.
//  * h multiplier: lane n32 holds ITS edge's h row in 8 f32x4 regs (global loads, L2-hit)
//    -> hsT buffer, its staging, and BOTH per-tile barriers are gone. Waves independent.
//  * bias: chained 2nd MFMA (A = bias col k=0 from 16-VGPR lane cache, B = ones row)
//    adds b[o] exactly; skipped via wave-uniform __any(bias!=0) (bias==0 here, exact
//    path preserved for nonzero bias).
//  * scatter: R10's proven pk-f16 atomics; D rows o come in adjacent-even reg pairs,
//    aggrH back to plain [node][o] layout.
// D/C layout (guide, m101-verified): col = lane&31 = edge, row o = (reg&3)+8*(reg>>2)
// +4*(lane>>5). A/B: lane&31 = m/n index, lane>>5 = K-halfblock (analog of 16x16x32).
// __launch_bounds__(256,1): cap 256 (empirical 256/arg2); est demand ~160, no spill.
__global__ void __launch_bounds__(256, 1)
k_edge(const short* __restrict__ WtP16,  // [1024][16] bf16 image
       const float* __restrict__ ea,     // [EE][16] f32
       const int* __restrict__ src,
       const int* __restrict__ dst,
       const float* __restrict__ h,
       __half* __restrict__ aggrH,       // [NN][32] f16 plain
       const float* __restrict__ b_edge) {
    __shared__ short W16[W16_SHORTS];    // 32768 B, linear layout

    int tid = threadIdx.x;
    // stage W16: 2048 uint4 / 256 threads = 8 each, linear
#pragma unroll
    for (int j = 0; j < 8; j++)
        ((uint4*)W16)[tid + 256 * j] = ((const uint4*)WtP16)[tid + 256 * j];

    const int lane = tid & 63;
    const int wave = tid >> 6;
    const int n32 = lane & 31, half = lane >> 5;
    const int gw = blockIdx.x * 4 + wave;          // global wave id, stride GSTRIDE

    // bias cache: bcp[g] packs bf16 b[(2g)*32+n32] | b[(2g+1)*32+n32]<<16  (16 VGPR)
    unsigned bcp[16];
    int nzf = 0;
#pragma unroll
    for (int g = 0; g < 16; g++) {
        float blo = b_edge[(2 * g) * 32 + n32];
        float bhi = b_edge[(2 * g + 1) * 32 + n32];
        nzf |= (blo != 0.f) | (bhi != 0.f);
        bcp[g] = (unsigned)(unsigned short)f2bf(blo) | ((unsigned)(unsigned short)f2bf(bhi) << 16);
    }
    const bool biasnz = __any(nzf);
    bf16x8 Bone = (bf16x8){0,0,0,0,0,0,0,0};
    if (half == 0) Bone[0] = (short)0x3F80;        // ones row at k=0

    __syncthreads();                                // W16 ready; no barriers after this

    const f32x16 Z16 = (f32x16)(0.f);

    struct PrefT {
        f32x4 hr[8];      // h row of my edge (32 f32)
        float4 e0, e1;    // ea[my edge][half*8 .. +8]
        int d;            // dst row
    };
    PrefT Pa, Pb;

    auto PREF = [&](int chk, PrefT& P) {
        int e = chk * 32 + n32;
        int s = src[e];
        P.d = dst[e];
        const f32x4* hp = (const f32x4*)(h + (size_t)s * CH);
#pragma unroll
        for (int j = 0; j < 8; j++) P.hr[j] = hp[j];
        const float4* ep = (const float4*)(ea + (size_t)e * FE + half * 8);
        P.e0 = ep[0]; P.e1 = ep[1];
    };

    auto COMPUTE = [&](PrefT& P) {
        bf16x8 Bea = cvt8(P.e0, P.e1);              // B[k][edge n32] = ea[edge][k]
        f32x16 m = Z16;
#pragma unroll
        for (int g = 0; g < 32; g++) {
            // A: rows co = g*32 + n32, k = half*8..+7 -> dense 1KB per wave, conflict-free
            bf16x8 Aw = *(const bf16x8*)(W16 + g * 512 + n32 * 16 + half * 8);
            f32x16 D = __builtin_amdgcn_mfma_f32_32x32x16_bf16(Aw, Bea, Z16, 0, 0, 0);
            if (biasnz) {                           // wave-uniform; exact bias add D += b[o]
                unsigned bw = bcp[g >> 1];
                short bs = (short)((g & 1) ? (bw >> 16) : (bw & 0xffffu));
                bf16x8 Ab = (bf16x8){0,0,0,0,0,0,0,0};
                if (half == 0) Ab[0] = bs;          // bias col at k=0
                D = __builtin_amdgcn_mfma_f32_32x32x16_bf16(Ab, Bone, D, 0, 0, 0);
            }
            float hv = P.hr[g >> 2][g & 3];         // h[my edge][c = g], static idx
#pragma unroll
            for (int r = 0; r < 16; r++) m[r] += lrelu(D[r]) * hv;
        }
        // scatter: 8 pk-f16 atomics; reg pair (2j,2j+1) = rows (o, o+1), o even
        __half* ap = (__half*)aggrH + (size_t)P.d * CH + 4 * half;
#pragma unroll
        for (int j = 0; j < 8; j++) {
            int ob = ((2 * j) & 3) + 8 * ((2 * j) >> 2);   // 0,2,8,10,16,18,24,26
            __half2 v = __floats2half2_rn(m[2 * j], m[2 * j + 1]);
            unsafeAtomicAdd((__half2*)(ap + ob), v);
        }
    };

    // grid-stride chunk loop, 2-phase unrolled (static Pa/Pb), NO barriers
    int ch = gw;                                    // gw < 4096 < NCH always
    PREF(ch, Pa);
    while (true) {
        int nch = ch + GSTRIDE;
        bool more = (nch < NCH);
        if (more) PREF(nch, Pb);                    // flies under COMPUTE
        COMPUTE(Pa);
        if (!more) break;
        ch = nch;

        nch = ch + GSTRIDE;
        more = (nch < NCH);
        if (more) PREF(nch, Pa);
        COMPUTE(Pb);
        if (!more) break;
        ch = nch;
    }
}

// ---------------- Kernel 3 (MFMA): out = leaky(aggr + h@W_root + b_conv) @ W_out + b_out
// aggrH plain [node][o] f16.
__global__ void __launch_bounds__(256)
k_node(const __half* __restrict__ aggrH,
       const float* __restrict__ h,
       const float* __restrict__ W_root,
       const float* __restrict__ b_conv,
       const float* __restrict__ W_out,
       const float* __restrict__ b_out,
       float* __restrict__ out) {
    __shared__ short WrB[CH * 40];   // W_root^T bf16: [o][c], stride 40 shorts (80B)
    __shared__ float WoS[CH];
    int tid = threadIdx.x;
    if (tid < 128) {
        int o = tid >> 2, c0 = (tid & 3) * 8;
        short tmp[8] __attribute__((aligned(16)));
#pragma unroll
        for (int j = 0; j < 8; j++) tmp[j] = f2bf(W_root[(c0 + j) * CH + o]);
        *(bf16x8*)&WrB[o * 40 + c0] = *(bf16x8*)tmp;
    } else if (tid < 160) {
        WoS[tid - 128] = W_out[tid - 128];
    }
    __syncthreads();

    int wave = tid >> 6, lane = tid & 63;
    int n16 = lane & 15, quad = lane >> 4;
    int node0 = blockIdx.x * 64 + wave * 16;

    int arow = node0 + n16; if (arow >= NN) arow = NN - 1;
    const float4* hp = (const float4*)(h + (size_t)arow * CH + quad * 8);
    float4 ha = hp[0], hb = hp[1];
    bf16x8 A = cvt8(ha, hb);
    float bc0 = b_conv[n16], bc1 = b_conv[16 + n16];
    f32x4 C0, C1;
#pragma unroll
    for (int r = 0; r < 4; r++) {
        int nr = node0 + quad * 4 + r; int cr = (nr < NN) ? nr : NN - 1;
        C0[r] = __half2float(aggrH[(size_t)cr * CH + n16]) + bc0;
        C1[r] = __half2float(aggrH[(size_t)cr * CH + 16 + n16]) + bc1;
    }
    bf16x8 B0 = *(const bf16x8*)&WrB[n16 * 40 + quad * 8];
    bf16x8 B1 = *(const bf16x8*)&WrB[(16 + n16) * 40 + quad * 8];
    f32x4 D0 = __builtin_amdgcn_mfma_f32_16x16x32_bf16(A, B0, C0, 0, 0, 0);
    f32x4 D1 = __builtin_amdgcn_mfma_f32_16x16x32_bf16(A, B1, C1, 0, 0, 0);

    float w0 = WoS[n16], w1 = WoS[16 + n16];
    f32x4 p;
#pragma unroll
    for (int r = 0; r < 4; r++)
        p[r] = lrelu(D0[r]) * w0 + lrelu(D1[r]) * w1;
#pragma unroll
    for (int mk = 1; mk < 16; mk <<= 1) {
#pragma unroll
        for (int r = 0; r < 4; r++) p[r] += __shfl_xor(p[r], mk, 64);
    }
    if (n16 == 0) {
        float bo = b_out[0];
#pragma unroll
        for (int r = 0; r < 4; r++) {
            int nr = node0 + quad * 4 + r;
            if (nr < NN) out[nr] = p[r] + bo;
        }
    }
}

extern "C" void kernel_launch(void* const* d_in, const int* in_sizes, int n_in,
                              void* d_out, int out_size, void* d_ws, size_t ws_size,
                              hipStream_t stream) {
    const float* x      = (const float*)d_in[0];
    const int*   ei     = (const int*)d_in[1];
    const float* ea     = (const float*)d_in[2];
    const float* W_in   = (const float*)d_in[3];
    const float* b_in   = (const float*)d_in[4];
    const float* W_edge = (const float*)d_in[5];
    const float* b_edge = (const float*)d_in[6];
    const float* W_root = (const float*)d_in[7];
    const float* b_conv = (const float*)d_in[8];
    const float* W_out  = (const float*)d_in[9];
    const float* b_out  = (const float*)d_in[10];
    float* out   = (float*)d_out;
    float* h     = (float*)d_ws;                      // [NN*CH] f32 (3.2MB)
    __half* aggrH = (__half*)(h + (size_t)NN * CH);   // [NN*CH] f16 plain (1.6MB)
    short* WtP16 = (short*)(aggrH + (size_t)NN * CH); // [1024*16] bf16 image

    k_pre<<<PROJ_BLOCKS + AUX_BLOCKS, 256, 0, stream>>>(x, W_in, b_in, W_edge, b_edge,
                                                        h, aggrH, WtP16);
    k_edge<<<EBLK, 256, 0, stream>>>(WtP16, ea, ei, ei + EE, h, aggrH, b_edge);
    k_node<<<PROJ_BLOCKS, 256, 0, stream>>>(aggrH, h, W_root, b_conv, W_out, b_out, out);
}